// Round 1
// baseline (245.724 us; speedup 1.0000x reference)
//
#include <hip/hip_runtime.h>

#define NB 4
#define NN 2048
#define CC 34
#define KF 32            // feature dims
#define NC 32            // m-chunks per row
#define MCH (NN / NC)    // 64 m's per chunk
#define RG  (NN / 64)    // 32 row-groups of 64 rows

__device__ __forceinline__ float wave_reduce_add_f(float v) {
#pragma unroll
    for (int off = 32; off > 0; off >>= 1) v += __shfl_xor(v, off, 64);
    return v;
}
__device__ __forceinline__ unsigned wave_reduce_add_u(unsigned v) {
#pragma unroll
    for (int off = 32; off > 0; off >>= 1) v += __shfl_xor(v, off, 64);
    return v;
}

// k1: fn = feat / max(||feat||, eps); q = emb[:, :2] + coords
__global__ void k1_norm(const float* __restrict__ emb, const float* __restrict__ crd,
                        float* __restrict__ fn, float* __restrict__ q) {
    int tid = blockIdx.x * blockDim.x + threadIdx.x;
    if (tid >= NB * NN) return;
    const float* e = emb + (size_t)tid * CC;
    float f[KF];
#pragma unroll
    for (int k2 = 0; k2 < KF / 2; ++k2) {
        float2 v = *reinterpret_cast<const float2*>(e + 2 + 2 * k2);  // 8B-aligned (row stride 136B)
        f[2 * k2] = v.x; f[2 * k2 + 1] = v.y;
    }
    float sq = 0.f;
#pragma unroll
    for (int k = 0; k < KF; ++k) sq = fmaf(f[k], f[k], sq);
    float scale = 1.0f / fmaxf(sqrtf(sq), 1e-8f);
#pragma unroll
    for (int k = 0; k < KF; ++k) fn[(size_t)tid * KF + k] = f[k] * scale;
    float2 c2 = *reinterpret_cast<const float2*>(crd + (size_t)tid * 2);
    q[2 * tid]     = e[0] + c2.x;
    q[2 * tid + 1] = e[1] + c2.y;
}

// k2: pair loop. Wave = (b, row-group of 64, m-chunk of 64). Lane owns one row.
__global__ __launch_bounds__(256) void k2_pairs(
    const float* __restrict__ fn, const float* __restrict__ q,
    float* __restrict__ Mws, float* __restrict__ Sws, unsigned* __restrict__ NPws,
    unsigned* __restrict__ cnt_lt, float* __restrict__ sig_sum)
{
    int wid = blockIdx.x * (blockDim.x >> 6) + (threadIdx.x >> 6);
    wid = __builtin_amdgcn_readfirstlane(wid);      // pin wave-uniform values to SGPR
    int lane = threadIdx.x & 63;
    int b  = wid >> 10;              // / (RG*NC)
    int rg = (wid >> 5) & (RG - 1);
    int c  = wid & (NC - 1);
    int n  = rg * 64 + lane;

    const float* fb = fn + (size_t)b * NN * KF;
    const float* qb = q  + (size_t)b * NN * 2;

    float fr[KF];
#pragma unroll
    for (int k4 = 0; k4 < KF / 4; ++k4) {
        float4 v = reinterpret_cast<const float4*>(fb + (size_t)n * KF)[k4];
        fr[4 * k4] = v.x; fr[4 * k4 + 1] = v.y; fr[4 * k4 + 2] = v.z; fr[4 * k4 + 3] = v.w;
    }
    float2 qn = reinterpret_cast<const float2*>(qb)[n];

    float M = -1e30f, S = 0.f, sig = 0.f;
    unsigned lt = 0;
    const int m0 = c * MCH;

    for (int i = 0; i < MCH; ++i) {
        int m = m0 + i;                                   // wave-uniform
        float2 qm = reinterpret_cast<const float2*>(qb)[m];
        float dx = qn.x - qm.x, dy = qn.y - qm.y;
        float dist = sqrtf(fmaf(dx, dx, dy * dy));
        sig += __builtin_amdgcn_rcpf(1.f + __expf(1.f - dist));   // sigmoid(dist-1)
        bool islt = dist < 1.0f;
        lt += islt ? 1u : 0u;

        float sim = 0.f;
        const float* fm = fb + (size_t)m * KF;            // wave-uniform address
#pragma unroll
        for (int k4 = 0; k4 < KF / 4; ++k4) {
            float4 v = reinterpret_cast<const float4*>(fm)[k4];
            sim = fmaf(fr[4 * k4],     v.x, sim);
            sim = fmaf(fr[4 * k4 + 1], v.y, sim);
            sim = fmaf(fr[4 * k4 + 2], v.z, sim);
            sim = fmaf(fr[4 * k4 + 3], v.w, sim);
        }
        bool ispos = islt && (m != n);
        float v = fmaf(-32.f, sim, 3.2f);                 // -ALPHA*(sim - MARGIN)
        float nM  = ispos ? fmaxf(M, v) : M;              // branchless online LSE
        float add = ispos ? __expf(v - nM) : 0.f;
        S = fmaf(S, __expf(M - nM), add);                 // M=-1e30 sentinel: exp() -> 0, no NaN
        M = nM;
    }

    size_t idx = ((size_t)(b * NN + n)) * NC + c;
    Mws[idx] = M; Sws[idx] = S; NPws[idx] = lt;

    float st = wave_reduce_add_f(sig);
    unsigned lts = wave_reduce_add_u(lt);
    if (lane == 0) {
        atomicAdd(sig_sum, st);
        atomicAdd(&cnt_lt[b], lts);
    }
}

// k3: per-row LSE merge + softplus, accumulate per batch
__global__ void k3_rows(const float* __restrict__ Mws, const float* __restrict__ Sws,
                        const unsigned* __restrict__ NPws, float* __restrict__ sp_sum) {
    int tid = blockIdx.x * blockDim.x + threadIdx.x;
    if (tid >= NB * NN) return;
    int b = tid >> 11;  // / NN
    float Mfin = 0.f;   // the >=1 zero entries (diagonal) anchor max at >= 0
    unsigned ltrow = 0;
#pragma unroll
    for (int c = 0; c < NC; ++c) {
        Mfin = fmaxf(Mfin, Mws[(size_t)tid * NC + c]);
        ltrow += NPws[(size_t)tid * NC + c];
    }
    float Ssum = 0.f;
#pragma unroll
    for (int c = 0; c < NC; ++c) {
        float Mc = Mws[(size_t)tid * NC + c];
        float Sc = Sws[(size_t)tid * NC + c];
        Ssum = fmaf(Sc, __expf(Mc - Mfin), Ssum);         // Mc=-1e30, Sc=0 -> contributes 0
    }
    float zeros = (float)(NN + 1 - (int)ltrow);           // N - (ltrow - 1) masked-out entries
    Ssum = fmaf(zeros, __expf(-Mfin), Ssum);
    float lse = Mfin + __logf(Ssum);                      // lse >= 0 always
    float sp = lse + log1pf(__expf(-lse));                // stable softplus for x>=0
    atomicAdd(&sp_sum[b], sp);
}

// k4: final scalar
__global__ void k4_final(const float* __restrict__ sig_sum, const float* __restrict__ sp_sum,
                         const unsigned* __restrict__ cnt_lt, float* __restrict__ out) {
    if (threadIdx.x == 0 && blockIdx.x == 0) {
        float tot = *sig_sum;
        for (int b = 0; b < NB; ++b) {
            float np = (float)((int)cnt_lt[b] - NN);              // num_pos = c_lt - N (diag always lt)
            float nn = (float)(NN * NN - (int)cnt_lt[b]);         // num_neg = N^2 - c_lt
            tot += sp_sum[b] * (1.f / (np + 1e-8f) + 1.f / (nn + 1e-8f));
        }
        out[0] = tot;
    }
}

extern "C" void kernel_launch(void* const* d_in, const int* in_sizes, int n_in,
                              void* d_out, int out_size, void* d_ws, size_t ws_size,
                              hipStream_t stream) {
    const float* emb = (const float*)d_in[0];
    const float* crd = (const float*)d_in[1];
    float* out = (float*)d_out;

    char* ws = (char*)d_ws;
    float* fn = (float*)ws;                                       // 1 MB
    float* q  = (float*)(ws + (size_t)NB * NN * KF * 4);          // 64 KB
    float* Mws = (float*)((char*)q + (size_t)NB * NN * 2 * 4);    // 1 MB
    float* Sws = Mws + (size_t)NB * NN * NC;                      // 1 MB
    unsigned* NPws = (unsigned*)(Sws + (size_t)NB * NN * NC);     // 1 MB
    float* sig_sum = (float*)(NPws + (size_t)NB * NN * NC);       // 4 B
    float* sp_sum  = sig_sum + 1;                                 // 16 B
    unsigned* cnt_lt = (unsigned*)(sp_sum + NB);                  // 16 B

    // zero the accumulators only (partial arrays are fully overwritten each call)
    hipMemsetAsync(sig_sum, 0, (1 + NB) * sizeof(float) + NB * sizeof(unsigned), stream);

    k1_norm<<<(NB * NN + 255) / 256, 256, 0, stream>>>(emb, crd, fn, q);
    k2_pairs<<<(NB * RG * NC) / 4, 256, 0, stream>>>(fn, q, Mws, Sws, NPws, cnt_lt, sig_sum);
    k3_rows<<<(NB * NN + 255) / 256, 256, 0, stream>>>(Mws, Sws, NPws, sp_sum);
    k4_final<<<1, 64, 0, stream>>>(sig_sum, sp_sum, cnt_lt, out);
}

// Round 2
// 192.051 us; speedup vs baseline: 1.2795x; 1.2795x over previous
//
#include <hip/hip_runtime.h>

#define NB 4
#define NN 2048
#define CC 34
#define KF 32            // feature dims
#define NC 64            // m-chunks per row
#define MCH (NN / NC)    // 32 m's per chunk
#define RG  (NN / 64)    // 32 row-groups of 64 rows

__device__ __forceinline__ float wave_reduce_add_f(float v) {
#pragma unroll
    for (int off = 32; off > 0; off >>= 1) v += __shfl_xor(v, off, 64);
    return v;
}

// k1: fn = feat / max(||feat||, eps); q = emb[:, :2] + coords
__global__ void k1_norm(const float* __restrict__ emb, const float* __restrict__ crd,
                        float* __restrict__ fn, float* __restrict__ q) {
    int tid = blockIdx.x * blockDim.x + threadIdx.x;
    if (tid >= NB * NN) return;
    const float* e = emb + (size_t)tid * CC;
    float f[KF];
#pragma unroll
    for (int k2 = 0; k2 < KF / 2; ++k2) {
        float2 v = *reinterpret_cast<const float2*>(e + 2 + 2 * k2);  // 8B-aligned (row stride 136B)
        f[2 * k2] = v.x; f[2 * k2 + 1] = v.y;
    }
    float sq = 0.f;
#pragma unroll
    for (int k = 0; k < KF; ++k) sq = fmaf(f[k], f[k], sq);
    float scale = 1.0f / fmaxf(sqrtf(sq), 1e-8f);
#pragma unroll
    for (int k = 0; k < KF; ++k) fn[(size_t)tid * KF + k] = f[k] * scale;
    float2 c2 = *reinterpret_cast<const float2*>(crd + (size_t)tid * 2);
    q[2 * tid]     = e[0] + c2.x;
    q[2 * tid + 1] = e[1] + c2.y;
}

// k2: pair loop. Wave = (b, row-group of 64, m-chunk of 32). Lane owns one row.
// No online max: v = -32*(sim-0.1) <= 35.2, exp(v) <= 2e15, row sum <= 4e18 << fp32 max.
__global__ __launch_bounds__(256, 4) void k2_pairs(
    const float* __restrict__ fn, const float* __restrict__ q,
    float* __restrict__ Srow, float* __restrict__ LTrow, float* __restrict__ sig_sum)
{
    int wid = blockIdx.x * 4 + (threadIdx.x >> 6);
    int lane = threadIdx.x & 63;
    int b  = wid >> 11;              // / (RG*NC)
    int rg = (wid >> 6) & (RG - 1);
    int c  = wid & (NC - 1);
    int n  = rg * 64 + lane;

    const float* fb = fn + (size_t)b * NN * KF;
    const float2* qb = (const float2*)(q + (size_t)b * NN * 2);

    float fr[KF];
#pragma unroll
    for (int k4 = 0; k4 < KF / 4; ++k4) {
        float4 v = reinterpret_cast<const float4*>(fb + (size_t)n * KF)[k4];
        fr[4 * k4] = v.x; fr[4 * k4 + 1] = v.y; fr[4 * k4 + 2] = v.z; fr[4 * k4 + 3] = v.w;
    }
    float2 qn = qb[n];

    float S = 0.f, sig = 0.f, ltf = 0.f;
    const int m0 = c * MCH;

#pragma unroll 2
    for (int i = 0; i < MCH; ++i) {
        int m = m0 + i;                                   // wave-uniform
        float2 qm = qb[m];
        const float4* fm = reinterpret_cast<const float4*>(fb + (size_t)m * KF);
        float4 w0 = fm[0], w1 = fm[1], w2 = fm[2], w3 = fm[3];
        float4 w4 = fm[4], w5 = fm[5], w6 = fm[6], w7 = fm[7];

        float dx = qn.x - qm.x, dy = qn.y - qm.y;
        float sq = fmaf(dx, dx, dy * dy);
        float dist = sqrtf(sq);
        sig += __builtin_amdgcn_rcpf(1.f + __expf(1.f - dist));   // sigmoid(dist-1)
        bool islt = sq < 1.0f;
        ltf += islt ? 1.f : 0.f;

        float sim = 0.f;
        sim = fmaf(fr[0],  w0.x, sim); sim = fmaf(fr[1],  w0.y, sim);
        sim = fmaf(fr[2],  w0.z, sim); sim = fmaf(fr[3],  w0.w, sim);
        sim = fmaf(fr[4],  w1.x, sim); sim = fmaf(fr[5],  w1.y, sim);
        sim = fmaf(fr[6],  w1.z, sim); sim = fmaf(fr[7],  w1.w, sim);
        sim = fmaf(fr[8],  w2.x, sim); sim = fmaf(fr[9],  w2.y, sim);
        sim = fmaf(fr[10], w2.z, sim); sim = fmaf(fr[11], w2.w, sim);
        sim = fmaf(fr[12], w3.x, sim); sim = fmaf(fr[13], w3.y, sim);
        sim = fmaf(fr[14], w3.z, sim); sim = fmaf(fr[15], w3.w, sim);
        sim = fmaf(fr[16], w4.x, sim); sim = fmaf(fr[17], w4.y, sim);
        sim = fmaf(fr[18], w4.z, sim); sim = fmaf(fr[19], w4.w, sim);
        sim = fmaf(fr[20], w5.x, sim); sim = fmaf(fr[21], w5.y, sim);
        sim = fmaf(fr[22], w5.z, sim); sim = fmaf(fr[23], w5.w, sim);
        sim = fmaf(fr[24], w6.x, sim); sim = fmaf(fr[25], w6.y, sim);
        sim = fmaf(fr[26], w6.z, sim); sim = fmaf(fr[27], w6.w, sim);
        sim = fmaf(fr[28], w7.x, sim); sim = fmaf(fr[29], w7.y, sim);
        sim = fmaf(fr[30], w7.z, sim); sim = fmaf(fr[31], w7.w, sim);

        float ev = __expf(fmaf(-32.f, sim, 3.2f));        // exp(-ALPHA*(sim-MARGIN))
        S += (islt && (m != n)) ? ev : 0.f;
    }

    atomicAdd(&Srow[b * NN + n], S);
    atomicAdd(&LTrow[b * NN + n], ltf);
    float st = wave_reduce_add_f(sig);
    if (lane == 0) atomicAdd(sig_sum, st);
}

// k3: per-row lse = log(S + (N+1-lt)); softplus; batch reduce sp and lt
__global__ void k3_rows(const float* __restrict__ Srow, const float* __restrict__ LTrow,
                        float* __restrict__ sp_sum, float* __restrict__ cnt) {
    int tid = blockIdx.x * blockDim.x + threadIdx.x;   // NB*NN threads
    int b = tid >> 11;                                  // wave-aligned: b uniform per wave
    float S = Srow[tid];
    float ltf = LTrow[tid];
    float zeros = (float)(NN + 1) - ltf;                // masked entries contribute exp(0)=1
    float lse = __logf(S + zeros);                      // >= 0 always (zeros >= 1)
    float sp = lse + log1pf(__expf(-lse));              // stable softplus for x>=0
    int lane = threadIdx.x & 63;
    float sps = wave_reduce_add_f(sp);
    float lts = wave_reduce_add_f(ltf);
    if (lane == 0) { atomicAdd(&sp_sum[b], sps); atomicAdd(&cnt[b], lts); }
}

// k4: final scalar
__global__ void k4_final(const float* __restrict__ sig_sum, const float* __restrict__ sp_sum,
                         const float* __restrict__ cnt, float* __restrict__ out) {
    if (threadIdx.x == 0 && blockIdx.x == 0) {
        float tot = *sig_sum;
        for (int b = 0; b < NB; ++b) {
            float np = cnt[b] - (float)NN;                        // num_pos = c_lt - N (diag always lt)
            float nn = (float)NN * (float)NN - cnt[b];            // num_neg = N^2 - c_lt
            tot += sp_sum[b] * (__builtin_amdgcn_rcpf(np + 1e-8f) +
                                __builtin_amdgcn_rcpf(nn + 1e-8f));
        }
        out[0] = tot;
    }
}

extern "C" void kernel_launch(void* const* d_in, const int* in_sizes, int n_in,
                              void* d_out, int out_size, void* d_ws, size_t ws_size,
                              hipStream_t stream) {
    const float* emb = (const float*)d_in[0];
    const float* crd = (const float*)d_in[1];
    float* out = (float*)d_out;

    float* ws = (float*)d_ws;
    float* Srow   = ws;                        // 8192
    float* LTrow  = Srow + NB * NN;            // 8192
    float* sig_sum = LTrow + NB * NN;          // 1
    float* sp_sum  = sig_sum + 1;              // 4
    float* cnt     = sp_sum + NB;              // 4
    float* fn = ws + 16400;                    // 262144 floats, 16B-aligned
    float* q  = fn + (size_t)NB * NN * KF;     // 16384 floats

    // zero accumulators (Srow, LTrow, scalars) — 65.6 KB
    hipMemsetAsync(ws, 0, 16400 * sizeof(float), stream);

    k1_norm<<<(NB * NN + 255) / 256, 256, 0, stream>>>(emb, crd, fn, q);
    k2_pairs<<<(NB * RG * NC) / 4, 256, 0, stream>>>(fn, q, Srow, LTrow, sig_sum);
    k3_rows<<<(NB * NN) / 256, 256, 0, stream>>>(Srow, LTrow, sp_sum, cnt);
    k4_final<<<1, 64, 0, stream>>>(sig_sum, sp_sum, cnt, out);
}

// Round 3
// 136.977 us; speedup vs baseline: 1.7939x; 1.4021x over previous
//
#include <hip/hip_runtime.h>

#define NB 4
#define NN 2048
#define CC 34
#define KF 32            // feature dims
#define NC 64            // m-chunks per row
#define MCH (NN / NC)    // 32 m's per chunk
#define RG  (NN / 64)    // 32 row-groups of 64 rows

__device__ __forceinline__ float wave_reduce_add_f(float v) {
#pragma unroll
    for (int off = 32; off > 0; off >>= 1) v += __shfl_xor(v, off, 64);
    return v;
}

// k1: fn = feat / max(||feat||, eps); q = emb[:, :2] + coords
__global__ void k1_norm(const float* __restrict__ emb, const float* __restrict__ crd,
                        float* __restrict__ fn, float* __restrict__ q) {
    int tid = blockIdx.x * blockDim.x + threadIdx.x;
    if (tid >= NB * NN) return;
    const float* e = emb + (size_t)tid * CC;
    float f[KF];
#pragma unroll
    for (int k2 = 0; k2 < KF / 2; ++k2) {
        float2 v = *reinterpret_cast<const float2*>(e + 2 + 2 * k2);  // 8B-aligned (row stride 136B)
        f[2 * k2] = v.x; f[2 * k2 + 1] = v.y;
    }
    float sq = 0.f;
#pragma unroll
    for (int k = 0; k < KF; ++k) sq = fmaf(f[k], f[k], sq);
    float scale = 1.0f / fmaxf(sqrtf(sq), 1e-8f);
#pragma unroll
    for (int k = 0; k < KF; ++k) fn[(size_t)tid * KF + k] = f[k] * scale;
    float2 c2 = *reinterpret_cast<const float2*>(crd + (size_t)tid * 2);
    q[2 * tid]     = e[0] + c2.x;
    q[2 * tid + 1] = e[1] + c2.y;
}

// k2: pair loop. Wave = (b, row-group of 64, m-chunk of 32). Lane owns one row (n).
// m-side addresses are wave-uniform (readfirstlane) -> s_load broadcast into SGPRs.
// fr[] pinned into VGPRs via asm so the compiler cannot sink the loads into the loop.
// No online max needed: v = -32*(sim-0.1) <= 35.2, exp(v) <= 2e15, row sum <= 4e18 << fp32 max.
__global__ __launch_bounds__(256, 4) void k2_pairs(
    const float* __restrict__ fn, const float* __restrict__ q,
    float* __restrict__ Srow, float* __restrict__ LTrow, float* __restrict__ sig_sum)
{
    int wid = blockIdx.x * 4 + (threadIdx.x >> 6);
    wid = __builtin_amdgcn_readfirstlane(wid);      // provably wave-uniform -> SGPR
    int lane = threadIdx.x & 63;
    int b  = wid >> 11;              // / (RG*NC)
    int rg = (wid >> 6) & (RG - 1);
    int c  = wid & (NC - 1);
    int n  = rg * 64 + lane;

    const float* fb = fn + (size_t)b * NN * KF;     // uniform base
    const float2* qb = (const float2*)(q + (size_t)b * NN * 2);

    float fr[KF];
#pragma unroll
    for (int k4 = 0; k4 < KF / 4; ++k4) {
        float4 v = reinterpret_cast<const float4*>(fb + (size_t)n * KF)[k4];
        fr[4 * k4] = v.x; fr[4 * k4 + 1] = v.y; fr[4 * k4 + 2] = v.z; fr[4 * k4 + 3] = v.w;
    }
#pragma unroll
    for (int k = 0; k < KF; ++k) asm volatile("" : "+v"(fr[k]));   // pin in VGPRs
    float2 qn = qb[n];
    asm volatile("" : "+v"(qn.x), "+v"(qn.y));

    float S = 0.f, sig = 0.f, ltf = 0.f;
    const int m0 = c * MCH;

#pragma unroll 2
    for (int i = 0; i < MCH; ++i) {
        int m = m0 + i;                                   // wave-uniform (SGPR)
        float2 qm = qb[m];                                // uniform -> s_load_dwordx2
        const float4* fm = reinterpret_cast<const float4*>(fb + (size_t)m * KF);
        float4 w0 = fm[0], w1 = fm[1], w2 = fm[2], w3 = fm[3];  // uniform -> s_load
        float4 w4 = fm[4], w5 = fm[5], w6 = fm[6], w7 = fm[7];

        float dx = qn.x - qm.x, dy = qn.y - qm.y;
        float sq = fmaf(dx, dx, dy * dy);
        float dist = sqrtf(sq);
        sig += __builtin_amdgcn_rcpf(1.f + __expf(1.f - dist));   // sigmoid(dist-1)
        bool islt = sq < 1.0f;
        ltf += islt ? 1.f : 0.f;

        float sim = 0.f;
        sim = fmaf(fr[0],  w0.x, sim); sim = fmaf(fr[1],  w0.y, sim);
        sim = fmaf(fr[2],  w0.z, sim); sim = fmaf(fr[3],  w0.w, sim);
        sim = fmaf(fr[4],  w1.x, sim); sim = fmaf(fr[5],  w1.y, sim);
        sim = fmaf(fr[6],  w1.z, sim); sim = fmaf(fr[7],  w1.w, sim);
        sim = fmaf(fr[8],  w2.x, sim); sim = fmaf(fr[9],  w2.y, sim);
        sim = fmaf(fr[10], w2.z, sim); sim = fmaf(fr[11], w2.w, sim);
        sim = fmaf(fr[12], w3.x, sim); sim = fmaf(fr[13], w3.y, sim);
        sim = fmaf(fr[14], w3.z, sim); sim = fmaf(fr[15], w3.w, sim);
        sim = fmaf(fr[16], w4.x, sim); sim = fmaf(fr[17], w4.y, sim);
        sim = fmaf(fr[18], w4.z, sim); sim = fmaf(fr[19], w4.w, sim);
        sim = fmaf(fr[20], w5.x, sim); sim = fmaf(fr[21], w5.y, sim);
        sim = fmaf(fr[22], w5.z, sim); sim = fmaf(fr[23], w5.w, sim);
        sim = fmaf(fr[24], w6.x, sim); sim = fmaf(fr[25], w6.y, sim);
        sim = fmaf(fr[26], w6.z, sim); sim = fmaf(fr[27], w6.w, sim);
        sim = fmaf(fr[28], w7.x, sim); sim = fmaf(fr[29], w7.y, sim);
        sim = fmaf(fr[30], w7.z, sim); sim = fmaf(fr[31], w7.w, sim);

        float ev = __expf(fmaf(-32.f, sim, 3.2f));        // exp(-ALPHA*(sim-MARGIN))
        S += (islt && (m != n)) ? ev : 0.f;
    }

    atomicAdd(&Srow[b * NN + n], S);
    atomicAdd(&LTrow[b * NN + n], ltf);
    float st = wave_reduce_add_f(sig);
    if (lane == 0) atomicAdd(sig_sum, st);
}

// k3: per-row lse = log(S + (N+1-lt)); softplus; batch reduce sp and lt
__global__ void k3_rows(const float* __restrict__ Srow, const float* __restrict__ LTrow,
                        float* __restrict__ sp_sum, float* __restrict__ cnt) {
    int tid = blockIdx.x * blockDim.x + threadIdx.x;   // NB*NN threads
    int b = tid >> 11;                                  // wave-aligned: b uniform per wave
    float S = Srow[tid];
    float ltf = LTrow[tid];
    float zeros = (float)(NN + 1) - ltf;                // masked entries contribute exp(0)=1
    float lse = __logf(S + zeros);                      // >= 0 always (zeros >= 1)
    float sp = lse + log1pf(__expf(-lse));              // stable softplus for x>=0
    int lane = threadIdx.x & 63;
    float sps = wave_reduce_add_f(sp);
    float lts = wave_reduce_add_f(ltf);
    if (lane == 0) { atomicAdd(&sp_sum[b], sps); atomicAdd(&cnt[b], lts); }
}

// k4: final scalar
__global__ void k4_final(const float* __restrict__ sig_sum, const float* __restrict__ sp_sum,
                         const float* __restrict__ cnt, float* __restrict__ out) {
    if (threadIdx.x == 0 && blockIdx.x == 0) {
        float tot = *sig_sum;
        for (int b = 0; b < NB; ++b) {
            float np = cnt[b] - (float)NN;                        // num_pos = c_lt - N (diag always lt)
            float nn = (float)NN * (float)NN - cnt[b];            // num_neg = N^2 - c_lt
            tot += sp_sum[b] * (__builtin_amdgcn_rcpf(np + 1e-8f) +
                                __builtin_amdgcn_rcpf(nn + 1e-8f));
        }
        out[0] = tot;
    }
}

extern "C" void kernel_launch(void* const* d_in, const int* in_sizes, int n_in,
                              void* d_out, int out_size, void* d_ws, size_t ws_size,
                              hipStream_t stream) {
    const float* emb = (const float*)d_in[0];
    const float* crd = (const float*)d_in[1];
    float* out = (float*)d_out;

    float* ws = (float*)d_ws;
    float* Srow   = ws;                        // 8192
    float* LTrow  = Srow + NB * NN;            // 8192
    float* sig_sum = LTrow + NB * NN;          // 1
    float* sp_sum  = sig_sum + 1;              // 4
    float* cnt     = sp_sum + NB;              // 4
    float* fn = ws + 16400;                    // 262144 floats, 16B-aligned
    float* q  = fn + (size_t)NB * NN * KF;     // 16384 floats

    // zero accumulators (Srow, LTrow, scalars) — 65.6 KB
    hipMemsetAsync(ws, 0, 16400 * sizeof(float), stream);

    k1_norm<<<(NB * NN + 255) / 256, 256, 0, stream>>>(emb, crd, fn, q);
    k2_pairs<<<(NB * RG * NC) / 4, 256, 0, stream>>>(fn, q, Srow, LTrow, sig_sum);
    k3_rows<<<(NB * NN) / 256, 256, 0, stream>>>(Srow, LTrow, sp_sum, cnt);
    k4_final<<<1, 64, 0, stream>>>(sig_sum, sp_sum, cnt, out);
}

// Round 4
// 63.851 us; speedup vs baseline: 3.8484x; 2.1453x over previous
//
#include <hip/hip_runtime.h>

#define NB 4
#define NN 2048
#define CC 34
#define KF 32            // feature dims
#define NC 32            // m-chunks per row
#define MCH (NN / NC)    // 64 m's per chunk
#define RG  32           // row-groups of 64 rows
#define NROW (NB * NN)   // 8192

__device__ __forceinline__ float wave_reduce_add_f(float v) {
#pragma unroll
    for (int off = 32; off > 0; off >>= 1) v += __shfl_xor(v, off, 64);
    return v;
}

// k1: fn = feat / max(||feat||, eps); q = emb[:, :2] + coords
__global__ void k1_norm(const float* __restrict__ emb, const float* __restrict__ crd,
                        float* __restrict__ fn, float* __restrict__ q) {
    int tid = blockIdx.x * blockDim.x + threadIdx.x;
    if (tid >= NROW) return;
    const float* e = emb + (size_t)tid * CC;
    float f[KF];
#pragma unroll
    for (int k2 = 0; k2 < KF / 2; ++k2) {
        float2 v = *reinterpret_cast<const float2*>(e + 2 + 2 * k2);  // 8B-aligned (row stride 136B)
        f[2 * k2] = v.x; f[2 * k2 + 1] = v.y;
    }
    float sq = 0.f;
#pragma unroll
    for (int k = 0; k < KF; ++k) sq = fmaf(f[k], f[k], sq);
    float scale = 1.0f / fmaxf(sqrtf(sq), 1e-8f);
#pragma unroll
    for (int k = 0; k < KF; ++k) fn[(size_t)tid * KF + k] = f[k] * scale;
    float2 c2 = *reinterpret_cast<const float2*>(crd + (size_t)tid * 2);
    q[2 * tid]     = e[0] + c2.x;
    q[2 * tid + 1] = e[1] + c2.y;
}

// k2: pair loop. Block = (b, m-chunk c, row-group-group rgg); wave w -> rg = rgg*4+w.
// Lane owns row n. m-side uniform -> s_load into SGPRs. NO global atomics on the hot
// path: per-(chunk,row) partials are written exclusively; sigmoid sum goes to 64
// spread buckets (one short atomic chain each).
// No online max needed: v = -32*(sim-0.1) <= 35.2, exp(v) <= 2e15, sum <= 4e18 << fp32 max.
__global__ __launch_bounds__(256, 4) void k2_pairs(
    const float* __restrict__ fn, const float* __restrict__ q,
    float* __restrict__ Spart, float* __restrict__ LTpart, float* __restrict__ sigbuf)
{
    int bid = blockIdx.x;
    int w = threadIdx.x >> 6, lane = threadIdx.x & 63;
    int b   = bid >> 8;              // 4
    int c   = (bid >> 3) & (NC - 1); // 32
    int rgg = bid & 7;               // 8
    int rg  = rgg * 4 + w;
    int n   = rg * 64 + lane;

    const float* fb = fn + (size_t)b * NN * KF;
    const float2* qb = (const float2*)(q + (size_t)b * NN * 2);
    int mbase = __builtin_amdgcn_readfirstlane(c * MCH);   // provably uniform

    float fr[KF];
#pragma unroll
    for (int k4 = 0; k4 < KF / 4; ++k4) {
        float4 v = reinterpret_cast<const float4*>(fb + (size_t)n * KF)[k4];
        fr[4 * k4] = v.x; fr[4 * k4 + 1] = v.y; fr[4 * k4 + 2] = v.z; fr[4 * k4 + 3] = v.w;
    }
#pragma unroll
    for (int k = 0; k < KF; ++k) asm volatile("" : "+v"(fr[k]));   // pin in VGPRs
    float2 qn = qb[n];
    asm volatile("" : "+v"(qn.x), "+v"(qn.y));

    float S = 0.f, sig = 0.f, ltf = 0.f;

#pragma unroll 2
    for (int i = 0; i < MCH; ++i) {
        int m = mbase + i;                                // wave-uniform (SGPR)
        float2 qm = qb[m];                                // s_load_dwordx2
        const float4* fm = reinterpret_cast<const float4*>(fb + (size_t)m * KF);
        float4 w0 = fm[0], w1 = fm[1], w2 = fm[2], w3 = fm[3];  // s_load_dwordx16 x2
        float4 w4 = fm[4], w5 = fm[5], w6 = fm[6], w7 = fm[7];

        float dx = qn.x - qm.x, dy = qn.y - qm.y;
        float sq = fmaf(dx, dx, dy * dy);
        float dist = sqrtf(sq);
        sig += __builtin_amdgcn_rcpf(1.f + __expf(1.f - dist));   // sigmoid(dist-1)
        bool islt = sq < 1.0f;
        ltf += islt ? 1.f : 0.f;

        float sim = 0.f;
        sim = fmaf(fr[0],  w0.x, sim); sim = fmaf(fr[1],  w0.y, sim);
        sim = fmaf(fr[2],  w0.z, sim); sim = fmaf(fr[3],  w0.w, sim);
        sim = fmaf(fr[4],  w1.x, sim); sim = fmaf(fr[5],  w1.y, sim);
        sim = fmaf(fr[6],  w1.z, sim); sim = fmaf(fr[7],  w1.w, sim);
        sim = fmaf(fr[8],  w2.x, sim); sim = fmaf(fr[9],  w2.y, sim);
        sim = fmaf(fr[10], w2.z, sim); sim = fmaf(fr[11], w2.w, sim);
        sim = fmaf(fr[12], w3.x, sim); sim = fmaf(fr[13], w3.y, sim);
        sim = fmaf(fr[14], w3.z, sim); sim = fmaf(fr[15], w3.w, sim);
        sim = fmaf(fr[16], w4.x, sim); sim = fmaf(fr[17], w4.y, sim);
        sim = fmaf(fr[18], w4.z, sim); sim = fmaf(fr[19], w4.w, sim);
        sim = fmaf(fr[20], w5.x, sim); sim = fmaf(fr[21], w5.y, sim);
        sim = fmaf(fr[22], w5.z, sim); sim = fmaf(fr[23], w5.w, sim);
        sim = fmaf(fr[24], w6.x, sim); sim = fmaf(fr[25], w6.y, sim);
        sim = fmaf(fr[26], w6.z, sim); sim = fmaf(fr[27], w6.w, sim);
        sim = fmaf(fr[28], w7.x, sim); sim = fmaf(fr[29], w7.y, sim);
        sim = fmaf(fr[30], w7.z, sim); sim = fmaf(fr[31], w7.w, sim);

        float ev = __expf(fmaf(-32.f, sim, 3.2f));        // exp(-ALPHA*(sim-MARGIN))
        S += (islt && (m != n)) ? ev : 0.f;
    }

    // exclusive-ownership partial writes: layout [c][b*NN + n] -> 64 consecutive floats/wave
    size_t pidx = (size_t)c * NROW + (size_t)b * NN + n;
    Spart[pidx]  = S;
    LTpart[pidx] = ltf;

    float st = wave_reduce_add_f(sig);
    if (lane == 0) atomicAdd(&sigbuf[(bid & 63) << 4], st);   // 64 buckets, 64B apart
}

// k3: per-row merge of NC chunk partials; lse = log(S + (N+1-lt)); softplus; batch reduce
__global__ void k3_rows(const float* __restrict__ Spart, const float* __restrict__ LTpart,
                        float* __restrict__ sp_sum, float* __restrict__ cnt) {
    int tid = blockIdx.x * blockDim.x + threadIdx.x;   // NROW threads
    float S = 0.f, ltf = 0.f;
#pragma unroll
    for (int c = 0; c < NC; ++c) {
        S   += Spart[(size_t)c * NROW + tid];
        ltf += LTpart[(size_t)c * NROW + tid];
    }
    int b = tid >> 11;                                  // wave-uniform
    float zeros = (float)(NN + 1) - ltf;                // masked entries contribute exp(0)=1
    float lse = __logf(S + zeros);                      // >= 0 always (zeros >= 1)
    float sp = lse + log1pf(__expf(-lse));              // stable softplus for x>=0
    int lane = threadIdx.x & 63;
    float sps = wave_reduce_add_f(sp);
    float lts = wave_reduce_add_f(ltf);
    if (lane == 0) { atomicAdd(&sp_sum[b], sps); atomicAdd(&cnt[b], lts); }
}

// k4: final scalar
__global__ void k4_final(const float* __restrict__ sigbuf, const float* __restrict__ sp_sum,
                         const float* __restrict__ cnt, float* __restrict__ out) {
    if (threadIdx.x == 0 && blockIdx.x == 0) {
        float tot = 0.f;
        for (int i = 0; i < 64; ++i) tot += sigbuf[i << 4];
        for (int b = 0; b < NB; ++b) {
            float np = cnt[b] - (float)NN;                        // num_pos = c_lt - N (diag always lt)
            float nn = (float)NN * (float)NN - cnt[b];            // num_neg = N^2 - c_lt
            tot += sp_sum[b] * (__builtin_amdgcn_rcpf(np + 1e-8f) +
                                __builtin_amdgcn_rcpf(nn + 1e-8f));
        }
        out[0] = tot;
    }
}

extern "C" void kernel_launch(void* const* d_in, const int* in_sizes, int n_in,
                              void* d_out, int out_size, void* d_ws, size_t ws_size,
                              hipStream_t stream) {
    const float* emb = (const float*)d_in[0];
    const float* crd = (const float*)d_in[1];
    float* out = (float*)d_out;

    float* ws = (float*)d_ws;
    float* sigbuf = ws;                            // 64 buckets * 16 stride = 1024 floats
    float* sp_sum = ws + 1024;                     // 4
    float* cnt    = ws + 1028;                     // 4
    float* fn     = ws + 1040;                     // 262144 floats (16B-aligned offset)
    float* q      = fn + (size_t)NROW * KF;        // 16384 floats
    float* Spart  = q + (size_t)NROW * 2;          // NC*NROW = 262144
    float* LTpart = Spart + (size_t)NC * NROW;     // 262144
    // total ~3.1 MB

    // zero only the accumulators (sigbuf + sp_sum + cnt)
    hipMemsetAsync(ws, 0, 1032 * sizeof(float), stream);

    k1_norm<<<NROW / 256, 256, 0, stream>>>(emb, crd, fn, q);
    k2_pairs<<<NB * NC * 8, 256, 0, stream>>>(fn, q, Spart, LTpart, sigbuf);
    k3_rows<<<NROW / 256, 256, 0, stream>>>(Spart, LTpart, sp_sum, cnt);
    k4_final<<<1, 64, 0, stream>>>(sigbuf, sp_sum, cnt, out);
}

// Round 5
// 47.994 us; speedup vs baseline: 5.1199x; 1.3304x over previous
//
#include <hip/hip_runtime.h>

#define NB 4
#define NN 2048
#define CC 34
#define KF 32              // feature dims (= MFMA K)
#define NCC 16             // col-chunks per row (128 cols each = 8 tiles)
#define NROW (NB * NN)     // 8192

typedef __attribute__((ext_vector_type(8))) short bf16x8;
typedef __attribute__((ext_vector_type(4))) float f32x4;

__device__ __forceinline__ float wave_reduce_add_f(float v) {
#pragma unroll
    for (int off = 32; off > 0; off >>= 1) v += __shfl_xor(v, off, 64);
    return v;
}
__device__ __forceinline__ unsigned short f2b(float x) {   // RNE float->bf16
    unsigned u = __float_as_uint(x);
    return (unsigned short)((u + 0x7fffu + ((u >> 16) & 1u)) >> 16);
}
__device__ __forceinline__ float b2f(unsigned short h) {
    return __uint_as_float((unsigned)h << 16);
}

// k1: per row -> fnb (normalized feat, bf16), Aq/Bq (dist^2 MFMA packing)
// dist^2(n,m) = an + am - 2 qn.qm via slots:
//  A = [xh,xh,xl, yh,yh,yl, ah,al, 1,1, 0...]
//  B = [-2xh,-2xl,-2xh, -2yh,-2yl,-2yh, 1,1, ah,al, 0...]
__global__ void k1_prep(const float* __restrict__ emb, const float* __restrict__ crd,
                        unsigned short* __restrict__ fnb, unsigned short* __restrict__ Aq,
                        unsigned short* __restrict__ Bq) {
    int tid = blockIdx.x * blockDim.x + threadIdx.x;
    if (tid >= NROW) return;
    const float* e = emb + (size_t)tid * CC;
    float f[KF];
#pragma unroll
    for (int k2 = 0; k2 < KF / 2; ++k2) {
        float2 v = *reinterpret_cast<const float2*>(e + 2 + 2 * k2);  // 8B-aligned
        f[2 * k2] = v.x; f[2 * k2 + 1] = v.y;
    }
    float sq = 0.f;
#pragma unroll
    for (int k = 0; k < KF; ++k) sq = fmaf(f[k], f[k], sq);
    float scale = 1.0f / fmaxf(sqrtf(sq), 1e-8f);
    unsigned short* frow = fnb + (size_t)tid * KF;
#pragma unroll
    for (int k = 0; k < KF; ++k) frow[k] = f2b(f[k] * scale);

    float2 c2 = *reinterpret_cast<const float2*>(crd + (size_t)tid * 2);
    float qx = e[0] + c2.x, qy = e[1] + c2.y;
    float an = fmaf(qx, qx, qy * qy);
    float xh = b2f(f2b(qx)), xl = qx - xh;
    float yh = b2f(f2b(qy)), yl = qy - yh;
    float ah = b2f(f2b(an)), al = an - ah;
    const unsigned short one = 0x3F80;

    unsigned short a[KF], bq[KF];
#pragma unroll
    for (int k = 0; k < KF; ++k) { a[k] = 0; bq[k] = 0; }
    a[0] = f2b(xh); a[1] = f2b(xh); a[2] = f2b(xl);
    a[3] = f2b(yh); a[4] = f2b(yh); a[5] = f2b(yl);
    a[6] = f2b(ah); a[7] = f2b(al); a[8] = one; a[9] = one;
    bq[0] = f2b(-2.f * xh); bq[1] = f2b(-2.f * xl); bq[2] = f2b(-2.f * xh);
    bq[3] = f2b(-2.f * yh); bq[4] = f2b(-2.f * yl); bq[5] = f2b(-2.f * yh);
    bq[6] = one; bq[7] = one; bq[8] = f2b(ah); bq[9] = f2b(al);
    unsigned short* arow = Aq + (size_t)tid * KF;
    unsigned short* brow = Bq + (size_t)tid * KF;
#pragma unroll
    for (int k = 0; k < KF; ++k) { arow[k] = a[k]; brow[k] = bq[k]; }
}

// k2: MFMA pair kernel. Wave = (b, 16-row strip, 128-col chunk); 8 tiles of 16x16.
// c1 = fn.fn^T (sim), c2 = dist^2 via packed MFMA. Epilogue: sigmoid-sum, count, exp-sum.
// No global atomics on partials (exclusive [cc][row] ownership).
__global__ __launch_bounds__(256, 4) void k2_pairs(
    const unsigned short* __restrict__ fnb, const unsigned short* __restrict__ Aq,
    const unsigned short* __restrict__ Bq,
    float* __restrict__ Spart, float* __restrict__ LTpart, float* __restrict__ sigbuf)
{
    int tid = threadIdx.x;
    int w = tid >> 6, l = tid & 63;
    int bid = blockIdx.x;
    int b  = bid >> 9;              // 4
    int cc = (bid >> 5) & (NCC - 1);// 16
    int sg = bid & 31;              // 32 strip-groups
    int strip = sg * 4 + w;         // 128 strips
    int rbase = strip * 16;
    int lrow = l & 15, kg = l >> 4;

    size_t arow = ((size_t)(b * NN + rbase + lrow)) * KF + kg * 8;
    bf16x8 fa  = *reinterpret_cast<const bf16x8*>(fnb + arow);
    bf16x8 faq = *reinterpret_cast<const bf16x8*>(Aq + arow);

    float Sa[4] = {0.f, 0.f, 0.f, 0.f};
    float La[4] = {0.f, 0.f, 0.f, 0.f};
    float sig = 0.f;
    const int col0 = cc * 128;

#pragma unroll
    for (int t = 0; t < 8; ++t) {
        int crow = col0 + t * 16 + lrow;                  // global col for this lane
        size_t bo = ((size_t)(b * NN + crow)) * KF + kg * 8;
        bf16x8 fb  = *reinterpret_cast<const bf16x8*>(fnb + bo);
        bf16x8 fbq = *reinterpret_cast<const bf16x8*>(Bq + bo);
        f32x4 z = {0.f, 0.f, 0.f, 0.f};
        f32x4 c1 = __builtin_amdgcn_mfma_f32_16x16x32_bf16(fa,  fb,  z, 0, 0, 0);
        f32x4 c2 = __builtin_amdgcn_mfma_f32_16x16x32_bf16(faq, fbq, z, 0, 0, 0);
#pragma unroll
        for (int r = 0; r < 4; ++r) {
            float sim = c1[r];
            float sqd = fmaxf(c2[r], 0.f);
            float dist = sqrtf(sqd);
            sig += __builtin_amdgcn_rcpf(1.f + __expf(1.f - dist));  // sigmoid(dist-1)
            bool islt = sqd < 1.f;
            La[r] += islt ? 1.f : 0.f;
            int grow = rbase + kg * 4 + r;                // global row (C row map, m89)
            float ev = __expf(fmaf(-32.f, sim, 3.2f));    // exp(-ALPHA*(sim-MARGIN))
            Sa[r] += (islt && (grow != crow)) ? ev : 0.f;
        }
    }

    // reduce across the 16 lanes holding the same 4 rows (different cols)
#pragma unroll
    for (int off = 1; off < 16; off <<= 1) {
#pragma unroll
        for (int r = 0; r < 4; ++r) {
            Sa[r] += __shfl_xor(Sa[r], off, 64);
            La[r] += __shfl_xor(La[r], off, 64);
        }
    }
    if (lrow == 0) {
#pragma unroll
        for (int r = 0; r < 4; ++r) {
            size_t R = (size_t)b * NN + rbase + kg * 4 + r;
            Spart[(size_t)cc * NROW + R]  = Sa[r];
            LTpart[(size_t)cc * NROW + R] = La[r];
        }
    }
    float st = wave_reduce_add_f(sig);
    if (l == 0) atomicAdd(&sigbuf[(bid & 63) << 4], st);   // 64 spread buckets
}

// k3: merge NCC chunk partials per row; lse = log(S + (N+1-lt)); softplus; batch reduce
__global__ void k3_rows(const float* __restrict__ Spart, const float* __restrict__ LTpart,
                        float* __restrict__ sp_sum, float* __restrict__ cnt) {
    int tid = blockIdx.x * blockDim.x + threadIdx.x;   // NROW threads
    float S = 0.f, ltf = 0.f;
#pragma unroll
    for (int c = 0; c < NCC; ++c) {
        S   += Spart[(size_t)c * NROW + tid];
        ltf += LTpart[(size_t)c * NROW + tid];
    }
    int b = tid >> 11;
    float zeros = (float)(NN + 1) - ltf;                // masked entries contribute exp(0)=1
    float lse = __logf(S + zeros);                      // >= 0 (zeros >= 1)
    float sp = lse + log1pf(__expf(-lse));              // stable softplus, x>=0
    int lane = threadIdx.x & 63;
    float sps = wave_reduce_add_f(sp);
    float lts = wave_reduce_add_f(ltf);
    if (lane == 0) { atomicAdd(&sp_sum[b], sps); atomicAdd(&cnt[b], lts); }
}

// k4: final scalar
__global__ void k4_final(const float* __restrict__ sigbuf, const float* __restrict__ sp_sum,
                         const float* __restrict__ cnt, float* __restrict__ out) {
    if (threadIdx.x == 0 && blockIdx.x == 0) {
        float tot = 0.f;
        for (int i = 0; i < 64; ++i) tot += sigbuf[i << 4];
        for (int b = 0; b < NB; ++b) {
            float np = cnt[b] - (float)NN;                        // num_pos = c_lt - N
            float nn = (float)NN * (float)NN - cnt[b];            // num_neg = N^2 - c_lt
            tot += sp_sum[b] * (__builtin_amdgcn_rcpf(np + 1e-8f) +
                                __builtin_amdgcn_rcpf(nn + 1e-8f));
        }
        out[0] = tot;
    }
}

extern "C" void kernel_launch(void* const* d_in, const int* in_sizes, int n_in,
                              void* d_out, int out_size, void* d_ws, size_t ws_size,
                              hipStream_t stream) {
    const float* emb = (const float*)d_in[0];
    const float* crd = (const float*)d_in[1];
    float* out = (float*)d_out;

    float* ws = (float*)d_ws;
    float* sigbuf = ws;                                 // 64 buckets * 16 stride
    float* sp_sum = ws + 1024;                          // 4
    float* cnt    = ws + 1028;                          // 4
    float* Spart  = ws + 1040;                          // NCC*NROW = 131072
    float* LTpart = Spart + (size_t)NCC * NROW;         // 131072
    unsigned short* fnb = (unsigned short*)(LTpart + (size_t)NCC * NROW);  // 262144 u16
    unsigned short* Aq  = fnb + (size_t)NROW * KF;      // 262144 u16
    unsigned short* Bq  = Aq + (size_t)NROW * KF;       // 262144 u16
    // total ~2.6 MB

    hipMemsetAsync(ws, 0, 1032 * sizeof(float), stream);  // accumulators only

    k1_prep<<<NROW / 256, 256, 0, stream>>>(emb, crd, fnb, Aq, Bq);
    k2_pairs<<<NB * NCC * 32, 256, 0, stream>>>(fnb, Aq, Bq, Spart, LTpart, sigbuf);
    k3_rows<<<NROW / 256, 256, 0, stream>>>(Spart, LTpart, sp_sum, cnt);
    k4_final<<<1, 64, 0, stream>>>(sigbuf, sp_sum, cnt, out);
}

// Round 6
// 34.650 us; speedup vs baseline: 7.0916x; 1.3851x over previous
//
#include <hip/hip_runtime.h>

#define NB 4
#define NN 2048
#define CC 34
#define KF 32              // feature dims (= MFMA K)
#define NCC 16             // col-chunks per row (128 cols each = 8 tiles)
#define NROW (NB * NN)     // 8192
#define NBLK2 (NB * NCC * 32)   // 2048 k2 blocks
#define NBLK3 32                // k3 blocks

typedef __attribute__((ext_vector_type(8))) short bf16x8;
typedef __attribute__((ext_vector_type(4))) float f32x4;

__device__ __forceinline__ float wave_reduce_add_f(float v) {
#pragma unroll
    for (int off = 32; off > 0; off >>= 1) v += __shfl_xor(v, off, 64);
    return v;
}
__device__ __forceinline__ unsigned short f2b(float x) {   // RNE float->bf16
    unsigned u = __float_as_uint(x);
    return (unsigned short)((u + 0x7fffu + ((u >> 16) & 1u)) >> 16);
}
__device__ __forceinline__ float b2f(unsigned short h) {
    return __uint_as_float((unsigned)h << 16);
}

// k1: per row -> fnb (normalized feat, bf16), Aq/Bq (dist^2 MFMA packing)
// dist^2(n,m) = an + am - 2 qn.qm via slots:
//  A = [xh,xh,xl, yh,yh,yl, ah,al, 1,1, 0...]
//  B = [-2xh,-2xl,-2xh, -2yh,-2yl,-2yh, 1,1, ah,al, 0...]
__global__ void k1_prep(const float* __restrict__ emb, const float* __restrict__ crd,
                        unsigned short* __restrict__ fnb, unsigned short* __restrict__ Aq,
                        unsigned short* __restrict__ Bq) {
    int tid = blockIdx.x * blockDim.x + threadIdx.x;
    if (tid >= NROW) return;
    const float* e = emb + (size_t)tid * CC;
    float f[KF];
#pragma unroll
    for (int k2 = 0; k2 < KF / 2; ++k2) {
        float2 v = *reinterpret_cast<const float2*>(e + 2 + 2 * k2);  // 8B-aligned
        f[2 * k2] = v.x; f[2 * k2 + 1] = v.y;
    }
    float sq = 0.f;
#pragma unroll
    for (int k = 0; k < KF; ++k) sq = fmaf(f[k], f[k], sq);
    float scale = 1.0f / fmaxf(sqrtf(sq), 1e-8f);
    unsigned short* frow = fnb + (size_t)tid * KF;
#pragma unroll
    for (int k = 0; k < KF; ++k) frow[k] = f2b(f[k] * scale);

    float2 c2 = *reinterpret_cast<const float2*>(crd + (size_t)tid * 2);
    float qx = e[0] + c2.x, qy = e[1] + c2.y;
    float an = fmaf(qx, qx, qy * qy);
    float xh = b2f(f2b(qx)), xl = qx - xh;
    float yh = b2f(f2b(qy)), yl = qy - yh;
    float ah = b2f(f2b(an)), al = an - ah;
    const unsigned short one = 0x3F80;

    unsigned short a[KF], bq[KF];
#pragma unroll
    for (int k = 0; k < KF; ++k) { a[k] = 0; bq[k] = 0; }
    a[0] = f2b(xh); a[1] = f2b(xh); a[2] = f2b(xl);
    a[3] = f2b(yh); a[4] = f2b(yh); a[5] = f2b(yl);
    a[6] = f2b(ah); a[7] = f2b(al); a[8] = one; a[9] = one;
    bq[0] = f2b(-2.f * xh); bq[1] = f2b(-2.f * xl); bq[2] = f2b(-2.f * xh);
    bq[3] = f2b(-2.f * yh); bq[4] = f2b(-2.f * yl); bq[5] = f2b(-2.f * yh);
    bq[6] = one; bq[7] = one; bq[8] = f2b(ah); bq[9] = f2b(al);
    unsigned short* arow = Aq + (size_t)tid * KF;
    unsigned short* brow = Bq + (size_t)tid * KF;
#pragma unroll
    for (int k = 0; k < KF; ++k) { arow[k] = a[k]; brow[k] = bq[k]; }
}

// k2: MFMA pair kernel, SWAPPED operands: mfma(fb_tile, fa_strip) so C col = n-row.
// Lane owns ONE output row n = rbase + (lane&15); its 4 acc elements are 4 m's.
// m-reduction is lane-local; only kg (xor 16,32) shuffle-reduce remains.
// No atomics, no zero-init: per-block exclusive sigpart slot.
__global__ __launch_bounds__(256, 4) void k2_pairs(
    const unsigned short* __restrict__ fnb, const unsigned short* __restrict__ Aq,
    const unsigned short* __restrict__ Bq,
    float* __restrict__ Spart, float* __restrict__ LTpart, float* __restrict__ sigpart)
{
    __shared__ float sred[4];
    int tid = threadIdx.x;
    int w = tid >> 6, l = tid & 63;
    int bid = blockIdx.x;
    int b  = bid >> 9;              // 4
    int cc = (bid >> 5) & (NCC - 1);// 16
    int sg = bid & 31;              // 32 strip-groups
    int strip = sg * 4 + w;         // 128 strips of 16 rows
    int rbase = strip * 16;
    int lrow = l & 15, kg = l >> 4;
    int kg4 = kg * 4;

    // fa: A-side strip (n rows). frag: lane row = l&15, k-slice = kg*8
    size_t arow = ((size_t)(b * NN + rbase + lrow)) * KF + kg * 8;
    bf16x8 fa  = *reinterpret_cast<const bf16x8*>(fnb + arow);
    bf16x8 faq = *reinterpret_cast<const bf16x8*>(Aq + arow);

    const int n = rbase + lrow;       // this lane's output row
    float S = 0.f, ltf = 0.f, sig = 0.f;
    const int col0 = cc * 128;

#pragma unroll
    for (int t = 0; t < 8; ++t) {
        int mrow = col0 + t * 16 + lrow;                  // fb frag row (m side)
        size_t bo = ((size_t)(b * NN + mrow)) * KF + kg * 8;
        bf16x8 fb  = *reinterpret_cast<const bf16x8*>(fnb + bo);
        bf16x8 fbq = *reinterpret_cast<const bf16x8*>(Bq + bo);
        f32x4 z = {0.f, 0.f, 0.f, 0.f};
        // swapped: C[i=m][j=n]; lane holds col j=l&15 (n), rows i=kg*4+r (m)
        f32x4 c1 = __builtin_amdgcn_mfma_f32_16x16x32_bf16(fb,  fa,  z, 0, 0, 0);
        f32x4 c2 = __builtin_amdgcn_mfma_f32_16x16x32_bf16(fbq, faq, z, 0, 0, 0);
#pragma unroll
        for (int r = 0; r < 4; ++r) {
            int m = col0 + t * 16 + kg4 + r;              // this element's m
            float sim = c1[r];
            float sqd = fmaxf(c2[r], 0.f);
            float dist = __builtin_amdgcn_sqrtf(sqd);
            sig += __builtin_amdgcn_rcpf(1.f + __expf(1.f - dist));  // sigmoid(dist-1)
            bool islt = sqd < 1.f;
            ltf += islt ? 1.f : 0.f;
            float ev = __expf(fmaf(-32.f, sim, 3.2f));    // exp(-ALPHA*(sim-MARGIN))
            S += (islt && (m != n)) ? ev : 0.f;
        }
    }

    // reduce across the 4 kg groups (lanes l, l^16, l^32, l^48) -> lanes 0..15 complete
    S   += __shfl_xor(S, 16, 64);   S   += __shfl_xor(S, 32, 64);
    ltf += __shfl_xor(ltf, 16, 64); ltf += __shfl_xor(ltf, 32, 64);
    if (kg == 0) {
        size_t R = (size_t)cc * NROW + (size_t)b * NN + rbase + lrow;  // coalesced x16
        Spart[R]  = S;
        LTpart[R] = ltf;
    }

    // block-exclusive sigmoid partial (no atomics, no zeroing)
    float st = wave_reduce_add_f(sig);
    if (l == 0) sred[w] = st;
    __syncthreads();
    if (tid == 0) sigpart[bid] = sred[0] + sred[1] + sred[2] + sred[3];
}

// k3: merge NCC chunk partials per row; softplus; per-block exclusive partials.
// Also each block folds a 64-slice of sigpart.
__global__ void k3_rows(const float* __restrict__ Spart, const float* __restrict__ LTpart,
                        const float* __restrict__ sigpart,
                        float* __restrict__ spB, float* __restrict__ cntB,
                        float* __restrict__ sigB) {
    __shared__ float red[8];
    int tid = blockIdx.x * blockDim.x + threadIdx.x;   // NROW threads
    int blk = blockIdx.x;
    float S = 0.f, ltf = 0.f;
#pragma unroll
    for (int c = 0; c < NCC; ++c) {
        S   += Spart[(size_t)c * NROW + tid];
        ltf += LTpart[(size_t)c * NROW + tid];
    }
    float zeros = (float)(NN + 1) - ltf;                // masked entries contribute exp(0)=1
    float lse = __logf(S + zeros);                      // >= 0 (zeros >= 1)
    float sp = lse + log1pf(__expf(-lse));              // stable softplus, x>=0
    int w = threadIdx.x >> 6, lane = threadIdx.x & 63;
    float sps = wave_reduce_add_f(sp);
    float lts = wave_reduce_add_f(ltf);
    if (lane == 0) { red[w] = sps; red[4 + w] = lts; }
    __syncthreads();
    if (threadIdx.x == 0) {
        spB[blk]  = red[0] + red[1] + red[2] + red[3];
        cntB[blk] = red[4] + red[5] + red[6] + red[7];
    }
    // fold sigpart slice: 64 entries per block, wave 1 handles it
    if (w == 1) {
        float sv = sigpart[blk * 64 + lane];
        sv = wave_reduce_add_f(sv);
        if (lane == 0) sigB[blk] = sv;
    }
}

// k4: final scalar (single wave; tiny)
__global__ void k4_final(const float* __restrict__ spB, const float* __restrict__ cntB,
                         const float* __restrict__ sigB, float* __restrict__ out) {
    if (threadIdx.x == 0 && blockIdx.x == 0) {
        float tot = 0.f;
        for (int i = 0; i < NBLK3; ++i) tot += sigB[i];
        for (int b = 0; b < NB; ++b) {
            float sp = 0.f, ct = 0.f;
            for (int j = 0; j < 8; ++j) {                 // 8 k3-blocks per batch
                sp += spB[b * 8 + j];
                ct += cntB[b * 8 + j];
            }
            float np = ct - (float)NN;                    // num_pos = c_lt - N
            float nn = (float)NN * (float)NN - ct;        // num_neg = N^2 - c_lt
            tot += sp * (__builtin_amdgcn_rcpf(np + 1e-8f) +
                         __builtin_amdgcn_rcpf(nn + 1e-8f));
        }
        out[0] = tot;
    }
}

extern "C" void kernel_launch(void* const* d_in, const int* in_sizes, int n_in,
                              void* d_out, int out_size, void* d_ws, size_t ws_size,
                              hipStream_t stream) {
    const float* emb = (const float*)d_in[0];
    const float* crd = (const float*)d_in[1];
    float* out = (float*)d_out;

    float* ws = (float*)d_ws;
    float* sigpart = ws;                                // 2048 (exclusive per k2 block)
    float* spB     = ws + 2048;                         // 32
    float* cntB    = ws + 2080;                         // 32
    float* sigB    = ws + 2112;                         // 32
    float* Spart   = ws + 2160;                         // NCC*NROW = 131072 (16B-aligned)
    float* LTpart  = Spart + (size_t)NCC * NROW;        // 131072
    unsigned short* fnb = (unsigned short*)(LTpart + (size_t)NCC * NROW);  // 262144 u16
    unsigned short* Aq  = fnb + (size_t)NROW * KF;      // 262144 u16
    unsigned short* Bq  = Aq + (size_t)NROW * KF;       // 262144 u16
    // every slot written every call -> no memset needed

    k1_prep<<<NROW / 256, 256, 0, stream>>>(emb, crd, fnb, Aq, Bq);
    k2_pairs<<<NBLK2, 256, 0, stream>>>(fnb, Aq, Bq, Spart, LTpart, sigpart);
    k3_rows<<<NBLK3, 256, 0, stream>>>(Spart, LTpart, sigpart, spB, cntB, sigB);
    k4_final<<<1, 64, 0, stream>>>(spB, cntB, sigB, out);
}

// Round 7
// 31.324 us; speedup vs baseline: 7.8446x; 1.1062x over previous
//
#include <hip/hip_runtime.h>

#define NB 4
#define NN 2048
#define CC 34
#define KF 32              // feature dims (= MFMA K)
#define NCC 16             // col-chunks per row (128 cols each = 8 tiles)
#define NROW (NB * NN)     // 8192
#define NBLK2 (NB * NCC * 32)   // 2048 k2 blocks = 8 blocks/CU
#define NBLK3 32                // k3 blocks

typedef __attribute__((ext_vector_type(8))) short bf16x8;
typedef __attribute__((ext_vector_type(8))) unsigned short u16x8;
typedef __attribute__((ext_vector_type(4))) float f32x4;

__device__ __forceinline__ float wave_reduce_add_f(float v) {
#pragma unroll
    for (int off = 32; off > 0; off >>= 1) v += __shfl_xor(v, off, 64);
    return v;
}
__device__ __forceinline__ unsigned short f2b(float x) {   // RNE float->bf16
    unsigned u = __float_as_uint(x);
    return (unsigned short)((u + 0x7fffu + ((u >> 16) & 1u)) >> 16);
}
__device__ __forceinline__ float b2f(unsigned short h) {
    return __uint_as_float((unsigned)h << 16);
}

// k1: per row -> fnb (normalized feat, bf16), Aq/Bq (dist^2 MFMA packing)
// dist^2(n,m) = an + am - 2 qn.qm via slots:
//  A = [xh,xh,xl, yh,yh,yl, ah,al, 1,1, 0...]
//  B = [-2xh,-2xl,-2xh, -2yh,-2yl,-2yh, 1,1, ah,al, 0...]
__global__ void k1_prep(const float* __restrict__ emb, const float* __restrict__ crd,
                        unsigned short* __restrict__ fnb, unsigned short* __restrict__ Aq,
                        unsigned short* __restrict__ Bq) {
    int tid = blockIdx.x * blockDim.x + threadIdx.x;
    if (tid >= NROW) return;
    const float* e = emb + (size_t)tid * CC;
    float f[KF];
#pragma unroll
    for (int k2 = 0; k2 < KF / 2; ++k2) {
        float2 v = *reinterpret_cast<const float2*>(e + 2 + 2 * k2);  // 8B-aligned
        f[2 * k2] = v.x; f[2 * k2 + 1] = v.y;
    }
    float sq = 0.f;
#pragma unroll
    for (int k = 0; k < KF; ++k) sq = fmaf(f[k], f[k], sq);
    float scale = 1.0f / fmaxf(sqrtf(sq), 1e-8f);
#pragma unroll
    for (int j = 0; j < 4; ++j) {
        u16x8 v;
#pragma unroll
        for (int k = 0; k < 8; ++k) v[k] = f2b(f[8 * j + k] * scale);
        *reinterpret_cast<u16x8*>(fnb + (size_t)tid * KF + 8 * j) = v;
    }

    float2 c2 = *reinterpret_cast<const float2*>(crd + (size_t)tid * 2);
    float qx = e[0] + c2.x, qy = e[1] + c2.y;
    float an = fmaf(qx, qx, qy * qy);
    float xh = b2f(f2b(qx)), xl = qx - xh;
    float yh = b2f(f2b(qy)), yl = qy - yh;
    float ah = b2f(f2b(an)), al = an - ah;
    const unsigned short one = 0x3F80;

    unsigned short* arow = Aq + (size_t)tid * KF;
    unsigned short* brow = Bq + (size_t)tid * KF;
    u16x8 zv = {0, 0, 0, 0, 0, 0, 0, 0};
    u16x8 a0 = {f2b(xh), f2b(xh), f2b(xl), f2b(yh), f2b(yh), f2b(yl), f2b(ah), f2b(al)};
    u16x8 a1 = {one, one, 0, 0, 0, 0, 0, 0};
    u16x8 b0 = {f2b(-2.f * xh), f2b(-2.f * xl), f2b(-2.f * xh),
                f2b(-2.f * yh), f2b(-2.f * yl), f2b(-2.f * yh), one, one};
    u16x8 b1 = {f2b(ah), f2b(al), 0, 0, 0, 0, 0, 0};
    *reinterpret_cast<u16x8*>(arow)      = a0;
    *reinterpret_cast<u16x8*>(arow + 8)  = a1;
    *reinterpret_cast<u16x8*>(arow + 16) = zv;
    *reinterpret_cast<u16x8*>(arow + 24) = zv;
    *reinterpret_cast<u16x8*>(brow)      = b0;
    *reinterpret_cast<u16x8*>(brow + 8)  = b1;
    *reinterpret_cast<u16x8*>(brow + 16) = zv;
    *reinterpret_cast<u16x8*>(brow + 24) = zv;
}

// k2: MFMA pair kernel, swapped operands (lane owns output row n = rbase+(l&15)).
// 1-deep software pipeline, <=64 VGPR target for 8 waves/SIMD.
__global__ __launch_bounds__(256, 8) void k2_pairs(
    const unsigned short* __restrict__ fnb, const unsigned short* __restrict__ Aq,
    const unsigned short* __restrict__ Bq,
    float* __restrict__ Spart, float* __restrict__ LTpart, float* __restrict__ sigpart)
{
    __shared__ float sred[4];
    int tid = threadIdx.x;
    int w = tid >> 6, l = tid & 63;
    int bid = blockIdx.x;
    int b  = bid >> 9;              // 4
    int cc = (bid >> 5) & (NCC - 1);// 16
    int sg = bid & 31;              // 32 strip-groups
    int strip = sg * 4 + w;         // 128 strips of 16 rows
    int rbase = strip * 16;
    int lrow = l & 15, kg = l >> 4;
    int kg4 = kg * 4;

    size_t arow = ((size_t)(b * NN + rbase + lrow)) * KF + kg * 8;
    bf16x8 fa  = *reinterpret_cast<const bf16x8*>(fnb + arow);
    bf16x8 faq = *reinterpret_cast<const bf16x8*>(Aq + arow);

    float S = 0.f, ltf = 0.f, sig = 0.f;
    const int col0 = cc * 128;
    const size_t bbase = (size_t)b * NN * KF + (size_t)col0 * KF + (size_t)lrow * KF + kg * 8;
    const unsigned short* fptr = fnb + bbase;
    const unsigned short* qptr = Bq + bbase;

    const float C1 = 1.44269504f;       // log2(e)
    const float C2 = -46.1662413f;      // -32*log2(e)
    const float C3 = 4.61662413f;       // 3.2*log2(e)

    bf16x8 fb0  = *reinterpret_cast<const bf16x8*>(fptr);
    bf16x8 fbq0 = *reinterpret_cast<const bf16x8*>(qptr);

#pragma unroll
    for (int t = 0; t < 8; ++t) {
        bf16x8 fb1, fbq1;
        if (t < 7) {
            fb1  = *reinterpret_cast<const bf16x8*>(fptr + (size_t)(t + 1) * 16 * KF);
            fbq1 = *reinterpret_cast<const bf16x8*>(qptr + (size_t)(t + 1) * 16 * KF);
        }
        f32x4 z = {0.f, 0.f, 0.f, 0.f};
        // swapped: C[i=m][j=n]; lane holds col j=l&15 (n), rows i=kg4+r (m)
        f32x4 c1 = __builtin_amdgcn_mfma_f32_16x16x32_bf16(fb0,  fa,  z, 0, 0, 0);
        f32x4 c2 = __builtin_amdgcn_mfma_f32_16x16x32_bf16(fbq0, faq, z, 0, 0, 0);

        if (col0 + t * 16 == rbase) {               // wave-uniform: diagonal tile
#pragma unroll
            for (int r = 0; r < 4; ++r) {
                float sim = c1[r];
                float sqd = fmaxf(c2[r], 0.f);
                float dist = __builtin_amdgcn_sqrtf(sqd);
                sig += __builtin_amdgcn_rcpf(1.f + __builtin_amdgcn_exp2f(fmaf(-C1, dist, C1)));
                bool islt = sqd < 1.f;
                ltf += islt ? 1.f : 0.f;
                float ev = __builtin_amdgcn_exp2f(fmaf(C2, sim, C3));
                S += (islt && (kg4 + r != lrow)) ? ev : 0.f;
            }
        } else {
#pragma unroll
            for (int r = 0; r < 4; ++r) {
                float sim = c1[r];
                float sqd = fmaxf(c2[r], 0.f);
                float dist = __builtin_amdgcn_sqrtf(sqd);
                sig += __builtin_amdgcn_rcpf(1.f + __builtin_amdgcn_exp2f(fmaf(-C1, dist, C1)));
                bool islt = sqd < 1.f;
                ltf += islt ? 1.f : 0.f;
                float ev = __builtin_amdgcn_exp2f(fmaf(C2, sim, C3));
                S += islt ? ev : 0.f;
            }
        }
        fb0 = fb1; fbq0 = fbq1;
    }

    // reduce across the 4 kg groups (lanes l, l^16, l^32, l^48) -> kg==0 lanes complete
    S   += __shfl_xor(S, 16, 64);   S   += __shfl_xor(S, 32, 64);
    ltf += __shfl_xor(ltf, 16, 64); ltf += __shfl_xor(ltf, 32, 64);
    if (kg == 0) {
        size_t R = (size_t)cc * NROW + (size_t)b * NN + rbase + lrow;  // coalesced x16
        Spart[R]  = S;
        LTpart[R] = ltf;
    }

    // block-exclusive sigmoid partial (no atomics, no zeroing)
    float st = wave_reduce_add_f(sig);
    if (l == 0) sred[w] = st;
    __syncthreads();
    if (tid == 0) sigpart[bid] = sred[0] + sred[1] + sred[2] + sred[3];
}

// k3: merge NCC chunk partials per row; softplus; per-block exclusive partials.
// Also each block folds a 64-slice of sigpart.
__global__ void k3_rows(const float* __restrict__ Spart, const float* __restrict__ LTpart,
                        const float* __restrict__ sigpart,
                        float* __restrict__ spB, float* __restrict__ cntB,
                        float* __restrict__ sigB) {
    __shared__ float red[8];
    int tid = blockIdx.x * blockDim.x + threadIdx.x;   // NROW threads
    int blk = blockIdx.x;
    float S = 0.f, ltf = 0.f;
#pragma unroll
    for (int c = 0; c < NCC; ++c) {
        S   += Spart[(size_t)c * NROW + tid];
        ltf += LTpart[(size_t)c * NROW + tid];
    }
    float zeros = (float)(NN + 1) - ltf;                // masked entries contribute exp(0)=1
    float lse = __logf(S + zeros);                      // >= 0 (zeros >= 1)
    float sp = lse + log1pf(__expf(-lse));              // stable softplus, x>=0
    int w = threadIdx.x >> 6, lane = threadIdx.x & 63;
    float sps = wave_reduce_add_f(sp);
    float lts = wave_reduce_add_f(ltf);
    if (lane == 0) { red[w] = sps; red[4 + w] = lts; }
    __syncthreads();
    if (threadIdx.x == 0) {
        spB[blk]  = red[0] + red[1] + red[2] + red[3];
        cntB[blk] = red[4] + red[5] + red[6] + red[7];
    }
    // fold sigpart slice: 64 entries per block, wave 1 handles it
    if (w == 1) {
        float sv = sigpart[blk * 64 + lane];
        sv = wave_reduce_add_f(sv);
        if (lane == 0) sigB[blk] = sv;
    }
}

// k4: final scalar (single wave; tiny)
__global__ void k4_final(const float* __restrict__ spB, const float* __restrict__ cntB,
                         const float* __restrict__ sigB, float* __restrict__ out) {
    if (threadIdx.x == 0 && blockIdx.x == 0) {
        float tot = 0.f;
        for (int i = 0; i < NBLK3; ++i) tot += sigB[i];
        for (int b = 0; b < NB; ++b) {
            float sp = 0.f, ct = 0.f;
            for (int j = 0; j < 8; ++j) {                 // 8 k3-blocks per batch
                sp += spB[b * 8 + j];
                ct += cntB[b * 8 + j];
            }
            float np = ct - (float)NN;                    // num_pos = c_lt - N
            float nn = (float)NN * (float)NN - ct;        // num_neg = N^2 - c_lt
            tot += sp * (__builtin_amdgcn_rcpf(np + 1e-8f) +
                         __builtin_amdgcn_rcpf(nn + 1e-8f));
        }
        out[0] = tot;
    }
}

extern "C" void kernel_launch(void* const* d_in, const int* in_sizes, int n_in,
                              void* d_out, int out_size, void* d_ws, size_t ws_size,
                              hipStream_t stream) {
    const float* emb = (const float*)d_in[0];
    const float* crd = (const float*)d_in[1];
    float* out = (float*)d_out;

    float* ws = (float*)d_ws;
    float* sigpart = ws;                                // 2048 (exclusive per k2 block)
    float* spB     = ws + 2048;                         // 32
    float* cntB    = ws + 2080;                         // 32
    float* sigB    = ws + 2112;                         // 32
    float* Spart   = ws + 2160;                         // NCC*NROW = 131072 (16B-aligned)
    float* LTpart  = Spart + (size_t)NCC * NROW;        // 131072
    unsigned short* fnb = (unsigned short*)(LTpart + (size_t)NCC * NROW);  // 262144 u16
    unsigned short* Aq  = fnb + (size_t)NROW * KF;      // 262144 u16
    unsigned short* Bq  = Aq + (size_t)NROW * KF;       // 262144 u16
    // every slot written every call -> no memset needed

    k1_prep<<<NROW / 256, 256, 0, stream>>>(emb, crd, fnb, Aq, Bq);
    k2_pairs<<<NBLK2, 256, 0, stream>>>(fnb, Aq, Bq, Spart, LTpart, sigpart);
    k3_rows<<<NBLK3, 256, 0, stream>>>(Spart, LTpart, sigpart, spB, cntB, sigB);
    k4_final<<<1, 64, 0, stream>>>(spB, cntB, sigB, out);
}